// Round 11
// baseline (536.880 us; speedup 1.0000x reference)
//
#include <hip/hip_runtime.h>
#include <stdint.h>

// R11: B-reuse via ray-doubling. R6 decomposition: 800k cyc/CU = B-restream
// (5.1 MB/CU at ~6.4 B/cyc effective L1/L2) >> MFMA (100k cyc). Weight bytes
// per block are fixed -> amortize over 2 rays/block (M=128). B fragments are
// loaded into 32 NAMED short8 regs once per layer (manual hoist; compiler
// can't CSE across __syncthreads) and reused for both row-halves.
// Peak regs ~233 <= 256 budget of (256,2). 2048 blocks, 2 blocks/CU.
// Sentinel: WRITE_SIZE <5 MB = no spill; >50 MB = revert.

#define NRAYS 4096

typedef unsigned short u16;
typedef __attribute__((ext_vector_type(8))) short short8;
typedef __attribute__((ext_vector_type(4))) float f32x4;

__device__ __forceinline__ u16 f2bf(float f) {
  union { float f; uint32_t i; } v; v.f = f;
  return (u16)((v.i + 0x7FFFu + ((v.i >> 16) & 1u)) >> 16);
}
__device__ __forceinline__ float bf2f(u16 u) {
  union { uint32_t i; float f; } v; v.i = ((uint32_t)u) << 16; return v.f;
}

// ---------------- weight transpose + fp32->bf16 convert into workspace ----------------
// ws (bf16 elems): W2t [256n][256k] @0, W3t [256n][256k] @65536, W4t [128n][256k] @131072
__global__ void pack_weights(const float* __restrict__ W2, const float* __restrict__ W3,
                             const float* __restrict__ W4, u16* __restrict__ ws) {
  int idx = blockIdx.x * 256 + threadIdx.x;   // grid covers exactly 163840
  float v;
  if (idx < 65536) {
    int n = idx >> 8, k = idx & 255;
    v = W2[k * 256 + n];
  } else if (idx < 131072) {
    int o = idx - 65536, n = o >> 8, k = o & 255;
    v = W3[k * 256 + n];
  } else {
    int o = idx - 131072, n = o >> 8, k = o & 255;
    v = W4[k * 128 + n];
  }
  ws[idx] = f2bf(v);
}

#define MFMA __builtin_amdgcn_mfma_f32_16x16x32_bf16
#define ZER4 (f32x4){0.f, 0.f, 0.f, 0.f}

// load the 4 B fragments for kc=k into named regs B{k}0..B{k}3
#define LDB4(k) \
    short8 B##k##0 = *(const short8*)(bp0 + ((k) * 4 + quad) * 8); \
    short8 B##k##1 = *(const short8*)(bp1 + ((k) * 4 + quad) * 8); \
    short8 B##k##2 = *(const short8*)(bp2 + ((k) * 4 + quad) * 8); \
    short8 B##k##3 = *(const short8*)(bp3 + ((k) * 4 + quad) * 8);

// one K-step vs row-base mb using pre-loaded B{k}*: 4 A ds_reads + 16 MFMA
#define KST4(k, mb) do {                                                      \
    const int sq = (k) * 4 + quad;                                            \
    const int a0r = (mb) + l15, a1r = (mb) + l15 + 16,                        \
              a2r = (mb) + l15 + 32, a3r = (mb) + l15 + 48;                   \
    short8 av0 = *(const short8*)(act + a0r * 256 + ((sq ^ (a0r & 31)) << 3)); \
    short8 av1 = *(const short8*)(act + a1r * 256 + ((sq ^ (a1r & 31)) << 3)); \
    short8 av2 = *(const short8*)(act + a2r * 256 + ((sq ^ (a2r & 31)) << 3)); \
    short8 av3 = *(const short8*)(act + a3r * 256 + ((sq ^ (a3r & 31)) << 3)); \
    c00 = MFMA(av0, B##k##0, c00, 0, 0, 0); c10 = MFMA(av1, B##k##0, c10, 0, 0, 0); \
    c20 = MFMA(av2, B##k##0, c20, 0, 0, 0); c30 = MFMA(av3, B##k##0, c30, 0, 0, 0); \
    c01 = MFMA(av0, B##k##1, c01, 0, 0, 0); c11 = MFMA(av1, B##k##1, c11, 0, 0, 0); \
    c21 = MFMA(av2, B##k##1, c21, 0, 0, 0); c31 = MFMA(av3, B##k##1, c31, 0, 0, 0); \
    c02 = MFMA(av0, B##k##2, c02, 0, 0, 0); c12 = MFMA(av1, B##k##2, c12, 0, 0, 0); \
    c22 = MFMA(av2, B##k##2, c22, 0, 0, 0); c32 = MFMA(av3, B##k##2, c32, 0, 0, 0); \
    c03 = MFMA(av0, B##k##3, c03, 0, 0, 0); c13 = MFMA(av1, B##k##3, c13, 0, 0, 0); \
    c23 = MFMA(av2, B##k##3, c23, 0, 0, 0); c33 = MFMA(av3, B##k##3, c33, 0, 0, 0); \
  } while (0)

// layer-4 variants: 2 col-tiles
#define LDB2(k) \
    short8 D##k##0 = *(const short8*)(bp0 + ((k) * 4 + quad) * 8); \
    short8 D##k##1 = *(const short8*)(bp1 + ((k) * 4 + quad) * 8);

#define KST2(k, mb) do {                                                      \
    const int sq = (k) * 4 + quad;                                            \
    const int a0r = (mb) + l15, a1r = (mb) + l15 + 16,                        \
              a2r = (mb) + l15 + 32, a3r = (mb) + l15 + 48;                   \
    short8 av0 = *(const short8*)(act + a0r * 256 + ((sq ^ (a0r & 31)) << 3)); \
    short8 av1 = *(const short8*)(act + a1r * 256 + ((sq ^ (a1r & 31)) << 3)); \
    short8 av2 = *(const short8*)(act + a2r * 256 + ((sq ^ (a2r & 31)) << 3)); \
    short8 av3 = *(const short8*)(act + a3r * 256 + ((sq ^ (a3r & 31)) << 3)); \
    c00 = MFMA(av0, D##k##0, c00, 0, 0, 0); c10 = MFMA(av1, D##k##0, c10, 0, 0, 0); \
    c20 = MFMA(av2, D##k##0, c20, 0, 0, 0); c30 = MFMA(av3, D##k##0, c30, 0, 0, 0); \
    c01 = MFMA(av0, D##k##1, c01, 0, 0, 0); c11 = MFMA(av1, D##k##1, c11, 0, 0, 0); \
    c21 = MFMA(av2, D##k##1, c21, 0, 0, 0); c31 = MFMA(av3, D##k##1, c31, 0, 0, 0); \
  } while (0)

#define ZERO16 c00=ZER4;c01=ZER4;c02=ZER4;c03=ZER4;c10=ZER4;c11=ZER4;c12=ZER4;c13=ZER4; \
               c20=ZER4;c21=ZER4;c22=ZER4;c23=ZER4;c30=ZER4;c31=ZER4;c32=ZER4;c33=ZER4;
#define ZERO8  c00=ZER4;c01=ZER4;c10=ZER4;c11=ZER4;c20=ZER4;c21=ZER4;c30=ZER4;c31=ZER4;

// store one 16x16 C-tile (absolute row-tile mta 0..7), column ng, relu(+addv)
#define EPIC(CV, mta, ng, addv) do {                                          \
    int su_ = ((ng) >> 3), so_ = ((ng) & 7);                                  \
    _Pragma("unroll")                                                         \
    for (int rr = 0; rr < 4; rr++) {                                          \
      int mm = (mta) * 16 + quad * 4 + rr;                                    \
      act[mm * 256 + ((su_ ^ (mm & 31)) << 3) + so_] =                        \
          f2bf(fmaxf((CV)[rr] + (addv), 0.f));                                \
    }                                                                         \
  } while (0)

__global__ void __launch_bounds__(256, 2) nerf_fused(
    const float* __restrict__ rays_o, const float* __restrict__ rays_d,
    const float* __restrict__ t_rand,
    const float* __restrict__ W1, const float* __restrict__ b1,
    const float* __restrict__ b2, const float* __restrict__ b3,
    const float* __restrict__ Wd, const float* __restrict__ bd,
    const float* __restrict__ W4, const float* __restrict__ b4,
    const float* __restrict__ W5, const float* __restrict__ b5,
    const u16* __restrict__ wpack, float* __restrict__ out) {
  __shared__ u16   act[128 * 256];   // 64 KB, XOR-swizzled slots, 2 rays x 64 samples
  __shared__ float zv[128];
  __shared__ float dist[128];
  __shared__ float dens[128];
  __shared__ float rgbL[128 * 4];
  __shared__ float vdirL[8];
  __shared__ float w5L[384];
  __shared__ float b5L[4];

  const int t = threadIdx.x;
  const int lane = t & 63;
  const int wv = t >> 6;        // 0..3 : col quarter
  const int quad = lane >> 4;
  const int l15 = lane & 15;
  const int ray0 = blockIdx.x * 2;

  // ---- setup ----
  if (t < 128) {
    int j = t & 63, r = t >> 6;
    float fj = (float)j;
    float zj = 0.5f + 2.0f * (fj / 63.0f);
    float lower = (j == 0)  ? zj : 0.5f * (zj + (0.5f + 2.0f * ((fj - 1.0f) / 63.0f)));
    float upper = (j == 63) ? zj : 0.5f * (zj + (0.5f + 2.0f * ((fj + 1.0f) / 63.0f)));
    float tr = t_rand[(ray0 + r) * 64 + j];
    zv[t] = lower + (upper - lower) * tr;
  } else {
    int idx = t - 128;                // 0..127
    w5L[idx] = W5[idx];
    w5L[idx + 128] = W5[idx + 128];
    w5L[idx + 256] = W5[idx + 256];
  }
  if (t < 3) b5L[t] = b5[t];
  if (t < 2) {
    float dx = rays_d[(ray0 + t) * 3 + 0];
    float dy = rays_d[(ray0 + t) * 3 + 1];
    float dz = rays_d[(ray0 + t) * 3 + 2];
    float nrm = sqrtf(dx * dx + dy * dy + dz * dz) + 1e-8f;
    vdirL[t * 4 + 0] = dx / nrm; vdirL[t * 4 + 1] = dy / nrm; vdirL[t * 4 + 2] = dz / nrm;
  }
  __syncthreads();

  if (t < 128) {
    int j = t & 63;
    dist[t] = (j < 63) ? (zv[t + 1] - zv[t]) : 1e10f;
  }

  // ---- layer 1: h1 = relu(pts@W1 + b1) -> act ----
  {
    int m = t >> 1, p = t & 1, r = m >> 6;
    float zm = zv[m];
    float px = rays_o[(ray0 + r) * 3 + 0] + rays_d[(ray0 + r) * 3 + 0] * zm;
    float py = rays_o[(ray0 + r) * 3 + 1] + rays_d[(ray0 + r) * 3 + 1] * zm;
    float pz = rays_o[(ray0 + r) * 3 + 2] + rays_d[(ray0 + r) * 3 + 2] * zm;
#pragma unroll
    for (int kk = 0; kk < 128; kk += 8) {
      int k0 = p * 128 + kk;
      f32x4 bva = *(const f32x4*)(b1 + k0);
      f32x4 bvb = *(const f32x4*)(b1 + k0 + 4);
      f32x4 w0a = *(const f32x4*)(W1 + k0);
      f32x4 w0b = *(const f32x4*)(W1 + k0 + 4);
      f32x4 w1a = *(const f32x4*)(W1 + 256 + k0);
      f32x4 w1b = *(const f32x4*)(W1 + 256 + k0 + 4);
      f32x4 w2a = *(const f32x4*)(W1 + 512 + k0);
      f32x4 w2b = *(const f32x4*)(W1 + 512 + k0 + 4);
      f32x4 sa = bva + px * w0a + py * w1a + pz * w2a;
      f32x4 sb = bvb + px * w0b + py * w1b + pz * w2b;
      short8 res;
      res[0] = (short)f2bf(fmaxf(sa[0], 0.f));
      res[1] = (short)f2bf(fmaxf(sa[1], 0.f));
      res[2] = (short)f2bf(fmaxf(sa[2], 0.f));
      res[3] = (short)f2bf(fmaxf(sa[3], 0.f));
      res[4] = (short)f2bf(fmaxf(sb[0], 0.f));
      res[5] = (short)f2bf(fmaxf(sb[1], 0.f));
      res[6] = (short)f2bf(fmaxf(sb[2], 0.f));
      res[7] = (short)f2bf(fmaxf(sb[3], 0.f));
      int u = (k0 >> 3) ^ (m & 31);
      *(short8*)(act + m * 256 + u * 8) = res;
    }
  }
  __syncthreads();

  // ---- layers 2 & 3: K=256, N=256; B in regs once, two row-halves ----
#pragma unroll 1
  for (int L = 0; L < 2; L++) {
    const u16* wB = wpack + L * 65536;
    const float* bb = (L == 0) ? b2 : b3;
    const u16* bp0 = wB + (wv * 64 +  0 + l15) * 256;
    const u16* bp1 = wB + (wv * 64 + 16 + l15) * 256;
    const u16* bp2 = wB + (wv * 64 + 32 + l15) * 256;
    const u16* bp3 = wB + (wv * 64 + 48 + l15) * 256;
    int ng0 = wv * 64 + l15;
    float bi0 = bb[ng0], bi1 = bb[ng0 + 16], bi2 = bb[ng0 + 32], bi3 = bb[ng0 + 48];
    LDB4(0) LDB4(1) LDB4(2) LDB4(3) LDB4(4) LDB4(5) LDB4(6) LDB4(7)
    f32x4 c00, c01, c02, c03, c10, c11, c12, c13, c20, c21, c22, c23, c30, c31, c32, c33;
    // half 0: rows 0..63
    ZERO16
    KST4(0, 0); KST4(1, 0); KST4(2, 0); KST4(3, 0);
    KST4(4, 0); KST4(5, 0); KST4(6, 0); KST4(7, 0);
    __syncthreads();               // all reads of rows 0..63 (h_in) done
    EPIC(c00, 0, ng0, bi0); EPIC(c10, 1, ng0, bi0);
    EPIC(c20, 2, ng0, bi0); EPIC(c30, 3, ng0, bi0);
    EPIC(c01, 0, ng0 + 16, bi1); EPIC(c11, 1, ng0 + 16, bi1);
    EPIC(c21, 2, ng0 + 16, bi1); EPIC(c31, 3, ng0 + 16, bi1);
    EPIC(c02, 0, ng0 + 32, bi2); EPIC(c12, 1, ng0 + 32, bi2);
    EPIC(c22, 2, ng0 + 32, bi2); EPIC(c32, 3, ng0 + 32, bi2);
    EPIC(c03, 0, ng0 + 48, bi3); EPIC(c13, 1, ng0 + 48, bi3);
    EPIC(c23, 2, ng0 + 48, bi3); EPIC(c33, 3, ng0 + 48, bi3);
    // half 1: rows 64..127 (disjoint from epilogue-0 writes; overlaps them)
    ZERO16
    KST4(0, 64); KST4(1, 64); KST4(2, 64); KST4(3, 64);
    KST4(4, 64); KST4(5, 64); KST4(6, 64); KST4(7, 64);
    __syncthreads();               // all reads of rows 64..127 done
    EPIC(c00, 4, ng0, bi0); EPIC(c10, 5, ng0, bi0);
    EPIC(c20, 6, ng0, bi0); EPIC(c30, 7, ng0, bi0);
    EPIC(c01, 4, ng0 + 16, bi1); EPIC(c11, 5, ng0 + 16, bi1);
    EPIC(c21, 6, ng0 + 16, bi1); EPIC(c31, 7, ng0 + 16, bi1);
    EPIC(c02, 4, ng0 + 32, bi2); EPIC(c12, 5, ng0 + 32, bi2);
    EPIC(c22, 6, ng0 + 32, bi2); EPIC(c32, 7, ng0 + 32, bi2);
    EPIC(c03, 4, ng0 + 48, bi3); EPIC(c13, 5, ng0 + 48, bi3);
    EPIC(c23, 6, ng0 + 48, bi3); EPIC(c33, 7, ng0 + 48, bi3);
    __syncthreads();               // act = h_out complete
  }

  // ---- density: fp32 dot(h3, Wd), 128 rows ----
  {
    int m = t >> 1, p = t & 1;
    float s = 0.f;
#pragma unroll
    for (int kk = 0; kk < 128; kk += 8) {
      int k0 = p * 128 + kk;
      short8 h = *(const short8*)(act + m * 256 + (((k0 >> 3) ^ (m & 31)) << 3));
      f32x4 wa = *(const f32x4*)(Wd + k0);
      f32x4 wb = *(const f32x4*)(Wd + k0 + 4);
      s += bf2f((u16)h[0]) * wa[0] + bf2f((u16)h[1]) * wa[1]
         + bf2f((u16)h[2]) * wa[2] + bf2f((u16)h[3]) * wa[3]
         + bf2f((u16)h[4]) * wb[0] + bf2f((u16)h[5]) * wb[1]
         + bf2f((u16)h[6]) * wb[2] + bf2f((u16)h[7]) * wb[3];
    }
    s += __shfl_xor(s, 1);
    if (p == 0) dens[m] = s + bd[0];
  }

  // ---- layer 4: h4 = relu(h3@W4[:256] + vdir-tail + b4), N=128; B in regs, two halves ----
  {
    const u16* wB = wpack + 131072;
    const u16* bp0 = wB + (wv * 32 +  0 + l15) * 256;
    const u16* bp1 = wB + (wv * 32 + 16 + l15) * 256;
    int ng0 = wv * 32 + l15, ng1 = ng0 + 16;
    LDB2(0) LDB2(1) LDB2(2) LDB2(3) LDB2(4) LDB2(5) LDB2(6) LDB2(7)
    f32x4 c00, c01, c10, c11, c20, c21, c30, c31;
    // half 0: rows 0..63 (ray 0)
    ZERO8
    KST2(0, 0); KST2(1, 0); KST2(2, 0); KST2(3, 0);
    KST2(4, 0); KST2(5, 0); KST2(6, 0); KST2(7, 0);
    __syncthreads();               // density + rows 0..63 reads done
    {
      float v0 = vdirL[0], v1 = vdirL[1], v2 = vdirL[2];
      float ad0 = b4[ng0] + v0 * W4[32768 + ng0] + v1 * W4[32896 + ng0] + v2 * W4[33024 + ng0];
      float ad1 = b4[ng1] + v0 * W4[32768 + ng1] + v1 * W4[32896 + ng1] + v2 * W4[33024 + ng1];
      EPIC(c00, 0, ng0, ad0); EPIC(c10, 1, ng0, ad0);
      EPIC(c20, 2, ng0, ad0); EPIC(c30, 3, ng0, ad0);
      EPIC(c01, 0, ng1, ad1); EPIC(c11, 1, ng1, ad1);
      EPIC(c21, 2, ng1, ad1); EPIC(c31, 3, ng1, ad1);
    }
    // half 1: rows 64..127 (ray 1)
    ZERO8
    KST2(0, 64); KST2(1, 64); KST2(2, 64); KST2(3, 64);
    KST2(4, 64); KST2(5, 64); KST2(6, 64); KST2(7, 64);
    __syncthreads();
    {
      float v0 = vdirL[4], v1 = vdirL[5], v2 = vdirL[6];
      float ad0 = b4[ng0] + v0 * W4[32768 + ng0] + v1 * W4[32896 + ng0] + v2 * W4[33024 + ng0];
      float ad1 = b4[ng1] + v0 * W4[32768 + ng1] + v1 * W4[32896 + ng1] + v2 * W4[33024 + ng1];
      EPIC(c00, 4, ng0, ad0); EPIC(c10, 5, ng0, ad0);
      EPIC(c20, 6, ng0, ad0); EPIC(c30, 7, ng0, ad0);
      EPIC(c01, 4, ng1, ad1); EPIC(c11, 5, ng1, ad1);
      EPIC(c21, 6, ng1, ad1); EPIC(c31, 7, ng1, ad1);
    }
  }
  __syncthreads();                 // act = h4, dens ready

  // ---- rgb = sigmoid(h4@W5 + b5) ----
  {
    int m = t >> 1, p = t & 1;
    float s0 = 0.f, s1 = 0.f, s2 = 0.f;
#pragma unroll
    for (int kk = 0; kk < 64; kk += 8) {
      int k0 = p * 64 + kk;
      short8 h = *(const short8*)(act + m * 256 + (((k0 >> 3) ^ (m & 31)) << 3));
#pragma unroll
      for (int j = 0; j < 8; j++) {
        float hv = bf2f((u16)h[j]);
        int k = k0 + j;
        s0 += hv * w5L[k * 3 + 0];
        s1 += hv * w5L[k * 3 + 1];
        s2 += hv * w5L[k * 3 + 2];
      }
    }
    s0 += __shfl_xor(s0, 1);
    s1 += __shfl_xor(s1, 1);
    s2 += __shfl_xor(s2, 1);
    if (p == 0) {
      rgbL[m * 4 + 0] = 1.f / (1.f + __expf(-(s0 + b5L[0])));
      rgbL[m * 4 + 1] = 1.f / (1.f + __expf(-(s1 + b5L[1])));
      rgbL[m * 4 + 2] = 1.f / (1.f + __expf(-(s2 + b5L[2])));
    }
  }
  __syncthreads();

  // ---- alpha compositing: 2 waves, one ray each ----
  if (t < 128) {
    int r = t >> 6, j = t & 63, m = t;
    float alpha = 1.f - __expf(-fmaxf(dens[m], 0.f) * dist[m]);
    float v = 1.f - alpha + 1e-10f;
    float pscan = v;
#pragma unroll
    for (int d = 1; d < 64; d <<= 1) {
      float o = __shfl_up(pscan, d);
      if (j >= d) pscan *= o;
    }
    float T = __shfl_up(pscan, 1);
    if (j == 0) T = 1.f;
    float w = alpha * T;
    float r0 = w * rgbL[m * 4 + 0];
    float r1 = w * rgbL[m * 4 + 1];
    float r2 = w * rgbL[m * 4 + 2];
    float dp = w * zv[m];
    float ac = w;
#pragma unroll
    for (int d = 32; d; d >>= 1) {
      r0 += __shfl_down(r0, d);
      r1 += __shfl_down(r1, d);
      r2 += __shfl_down(r2, d);
      dp += __shfl_down(dp, d);
      ac += __shfl_down(ac, d);
    }
    if (j == 0) {
      int ray = ray0 + r;
      float bg = 1.f - ac;
      out[ray * 3 + 0] = r0 + bg;
      out[ray * 3 + 1] = r1 + bg;
      out[ray * 3 + 2] = r2 + bg;
      out[NRAYS * 3 + ray] = dp;
      out[NRAYS * 4 + ray] = ac;
    }
  }
}

extern "C" void kernel_launch(void* const* d_in, const int* in_sizes, int n_in,
                              void* d_out, int out_size, void* d_ws, size_t ws_size,
                              hipStream_t stream) {
  const float* rays_o = (const float*)d_in[0];
  const float* rays_d = (const float*)d_in[1];
  const float* t_rand = (const float*)d_in[2];
  const float* W1 = (const float*)d_in[3];
  const float* b1 = (const float*)d_in[4];
  const float* W2 = (const float*)d_in[5];
  const float* b2 = (const float*)d_in[6];
  const float* W3 = (const float*)d_in[7];
  const float* b3 = (const float*)d_in[8];
  const float* Wd = (const float*)d_in[9];
  const float* bd = (const float*)d_in[10];
  const float* W4 = (const float*)d_in[11];
  const float* b4 = (const float*)d_in[12];
  const float* W5 = (const float*)d_in[13];
  const float* b5 = (const float*)d_in[14];
  u16* wpack = (u16*)d_ws;
  float* out = (float*)d_out;

  pack_weights<<<640, 256, 0, stream>>>(W2, W3, W4, wpack);
  nerf_fused<<<NRAYS / 2, 256, 0, stream>>>(rays_o, rays_d, t_rand, W1, b1, b2, b3,
                                            Wd, bd, W4, b4, W5, b5, wpack, out);
}